// Round 4
// baseline (411.237 us; speedup 1.0000x reference)
//
#include <hip/hip_runtime.h>

typedef unsigned short u16;
typedef unsigned int u32;
typedef __attribute__((ext_vector_type(8))) short bf16x8;
typedef __attribute__((ext_vector_type(4))) float f32x4;
typedef __attribute__((ext_vector_type(8))) u16 u16x8;
typedef __attribute__((ext_vector_type(4))) u16 u16x4;

#define DEV __device__ __forceinline__

DEV u16 f2bf(float f) {
  u32 x = __float_as_uint(f);
  return (u16)((x + 0x7fffu + ((x >> 16) & 1u)) >> 16);  // RNE
}

// Problem dims: B=8 S=512 H=768 E=8 F=3072 K=2. fp32 I/O; internal bf16 MFMA.

// ---------- convert hidden fp32->bf16 + pooled sums (register-accumulated) ----------
// grid (64 s-chunks, 8 b) x 192 threads; thread t owns columns t*4..t*4+3 of 8 rows.
__global__ void convert_pool_kernel(const float* __restrict__ hidden, u16* __restrict__ hbf,
                                    float* __restrict__ pooled) {
  const int b = blockIdx.y, chunk = blockIdx.x, t = threadIdx.x;  // t in [0,192)
  const size_t base = (size_t)b * 512 * 768 + (size_t)chunk * 8 * 768 + t * 4;
  float ax = 0.f, ay = 0.f, az = 0.f, aw = 0.f;
#pragma unroll
  for (int r = 0; r < 8; ++r) {
    const float4 v = *(const float4*)(hidden + base + r * 768);
    ax += v.x; ay += v.y; az += v.z; aw += v.w;
    u16x4 o; o[0] = f2bf(v.x); o[1] = f2bf(v.y); o[2] = f2bf(v.z); o[3] = f2bf(v.w);
    *(u16x4*)(hbf + base + r * 768) = o;
  }
  float* p = pooled + b * 768 + t * 4;
  atomicAdd(p + 0, ax); atomicAdd(p + 1, ay);
  atomicAdd(p + 2, az); atomicAdd(p + 3, aw);
}

// ---------- router finalize: logits = pooled@Wg/512, softmax, top2 ----------
__global__ void router_final_kernel(const float* __restrict__ pooled, const float* __restrict__ Wg,
                                    float* __restrict__ logits_out, int* __restrict__ sel,
                                    float* __restrict__ wsel) {
  __shared__ float l8[64];
  const int tid = threadIdx.x;
  const int b = tid >> 5, r = tid & 31, e = r >> 2, q = r & 3;
  float p = 0.f;
  for (int h = q * 192; h < q * 192 + 192; ++h) p += pooled[b * 768 + h] * Wg[h * 8 + e];
  p += __shfl_xor(p, 1);
  p += __shfl_xor(p, 2);
  if (q == 0) {
    const float lg = p * (1.f / 512.f);
    l8[b * 8 + e] = lg;
    logits_out[b * 8 + e] = lg;
  }
  __syncthreads();
  if (tid < 8) {
    const int bb = tid;
    float mx = -1e30f;
    for (int i = 0; i < 8; ++i) mx = fmaxf(mx, l8[bb * 8 + i]);
    float w[8], ssum = 0.f;
    for (int i = 0; i < 8; ++i) { w[i] = __expf(l8[bb * 8 + i] - mx); ssum += w[i]; }
    for (int i = 0; i < 8; ++i) w[i] /= ssum;
    int i0 = 0;
    for (int i = 1; i < 8; ++i) if (w[i] > w[i0]) i0 = i;   // first-occurrence ties (jax top_k)
    int i1 = (i0 == 0) ? 1 : 0;
    for (int i = 0; i < 8; ++i) if (i != i0 && w[i] > w[i1]) i1 = i;
    sel[bb * 2 + 0] = i0; sel[bb * 2 + 1] = i1;
    wsel[bb * 2 + 0] = w[i0]; wsel[bb * 2 + 1] = w[i1];
  }
}

// ---------- 64x64 tiled transpose, fp32 src -> bf16 dst, wide LDS reads ----------
// block = 128 threads, one 64x64 tile. Read side: ds_read_b64 (4 cols) x 8 rows,
// 8x4 register transpose, 4 x 16B global stores.
__global__ void transpose_kernel(const float* __restrict__ src, u16* __restrict__ dst,
                                 int R, int C) {
  __shared__ u16 tile[64][68];  // 136B row stride (8B-aligned, +8B pad)
  const int e = blockIdx.z;
  src += (size_t)e * (size_t)R * C;
  dst += (size_t)e * (size_t)R * C;
  const int r0 = blockIdx.y * 64, c0 = blockIdx.x * 64;
  const int t = threadIdx.x;  // [0,128)
#pragma unroll
  for (int i = 0; i < 8; ++i) {
    const int ch = i * 128 + t;                 // 0..1023 float4 chunks
    const int row = ch >> 4, c4 = (ch & 15) * 4;
    const float4 v = *(const float4*)(src + (size_t)(r0 + row) * C + c0 + c4);
    u16x4 o; o[0] = f2bf(v.x); o[1] = f2bf(v.y); o[2] = f2bf(v.z); o[3] = f2bf(v.w);
    *(u16x4*)(&tile[row][c4]) = o;
  }
  __syncthreads();
  const int cg = t & 15, rg = t >> 4;           // 16 col-groups x 8 row-groups
  const int c4 = cg * 4, r8 = rg * 8;
  u16x4 rv[8];
#pragma unroll
  for (int j = 0; j < 8; ++j) rv[j] = *(const u16x4*)(&tile[r8 + j][c4]);
#pragma unroll
  for (int i = 0; i < 4; ++i) {
    u16x8 o;
#pragma unroll
    for (int j = 0; j < 8; ++j) o[j] = rv[j][i];
    *(u16x8*)(dst + (size_t)(c0 + c4 + i) * R + r0 + r8) = o;
  }
}

// ---------- GEMM core (m97 structure): 128x128 tile, BK=64, 16x16x32 bf16 ----------
DEV void stage_tile(const u16* __restrict__ gbase, int ld, int row0, int k0,
                    u16* lds, int tid) {
  const int crow = tid >> 3;
  const int ccol = (tid & 7) * 8;
  const int wbase = tid & ~63;
#pragma unroll
  for (int i = 0; i < 4; ++i) {
    const u16* g = gbase + (size_t)(row0 + i * 32 + crow) * ld + k0 + ccol;
    u16* l = lds + (size_t)(i * 256 + wbase) * 8;
    __builtin_amdgcn_global_load_lds((const __attribute__((address_space(1))) void*)g,
                                     (__attribute__((address_space(3))) void*)l, 16, 0, 0);
  }
}

DEV void mfma_step(const u16* As, const u16* Bs, int wm, int wn, int mi, int kq,
                   f32x4 acc[4][4]) {
#pragma unroll
  for (int s2 = 0; s2 < 64; s2 += 32) {
    bf16x8 af[4], bfr[4];
#pragma unroll
    for (int mt = 0; mt < 4; ++mt)
      af[mt] = *(const bf16x8*)(As + (wm + mt * 16 + mi) * 64 + s2 + kq * 8);
#pragma unroll
    for (int nt = 0; nt < 4; ++nt)
      bfr[nt] = *(const bf16x8*)(Bs + (wn + nt * 16 + mi) * 64 + s2 + kq * 8);
#pragma unroll
    for (int mt = 0; mt < 4; ++mt)
#pragma unroll
      for (int nt = 0; nt < 4; ++nt)
        acc[mt][nt] = __builtin_amdgcn_mfma_f32_16x16x32_bf16(af[mt], bfr[nt], acc[mt][nt], 0, 0, 0);
  }
}

// ---------- GEMM1: hbuf = wgt * gelu(hbf @ W1[e] + b1[e]), bf16 out ----------
__global__ void gemm1_kernel(const u16* __restrict__ hbf, const u16* __restrict__ w1t,
                             const float* __restrict__ b1, u16* __restrict__ hbuf,
                             const int* __restrict__ sel, const float* __restrict__ wsel) {
  __shared__ __align__(16) u16 As[128 * 64];
  __shared__ __align__(16) u16 Bs[128 * 64];
  const int p = blockIdx.z;
  const int b = p >> 1;
  const int e = sel[p];
  const float wgt = wsel[p];
  const u16* A = hbf + (size_t)b * 512 * 768;
  const u16* Bt = w1t + (size_t)e * 3072 * 768;
  const int m0 = blockIdx.y * 128, n0 = blockIdx.x * 128;
  const int tid = threadIdx.x, lane = tid & 63;
  const int wv = tid >> 6;
  const int wm = (wv >> 1) * 64, wn = (wv & 1) * 64;
  const int mi = lane & 15, kq = lane >> 4;

  f32x4 acc[4][4] = {};
  for (int k0 = 0; k0 < 768; k0 += 64) {
    __syncthreads();
    stage_tile(A, 768, m0, k0, As, tid);
    stage_tile(Bt, 768, n0, k0, Bs, tid);
    __syncthreads();
    mfma_step(As, Bs, wm, wn, mi, kq, acc);
  }

  const float* b1e = b1 + e * 3072;
  u16* C = hbuf + (size_t)p * 512 * 3072;
#pragma unroll
  for (int nt = 0; nt < 4; ++nt) {
    const int col = n0 + wn + nt * 16 + mi;
    const float bias = b1e[col];
#pragma unroll
    for (int mt = 0; mt < 4; ++mt) {
#pragma unroll
      for (int r = 0; r < 4; ++r) {
        const int row = m0 + wm + mt * 16 + kq * 4 + r;  // C/D: col=lane&15, row=quad*4+reg
        const float x = acc[mt][nt][r] + bias;
        const float g = 0.5f * x * (1.f + erff(x * 0.70710678118654752f));  // exact GELU
        C[(size_t)row * 3072 + col] = f2bf(wgt * g);
      }
    }
  }
}

// ---------- init d_out with weighted bias ----------
__global__ void init_out_kernel(const float* __restrict__ b2, float* __restrict__ out,
                                const int* __restrict__ sel, const float* __restrict__ wsel) {
  const int b = blockIdx.y;
  const int e0 = sel[b * 2 + 0], e1 = sel[b * 2 + 1];
  const float w0 = wsel[b * 2 + 0], w1 = wsel[b * 2 + 1];
  const int idx = blockIdx.x * 256 + threadIdx.x;   // float4 index in [0, 98304)
  const int h = (idx % 192) * 4;
  const float4 v0 = *(const float4*)(b2 + e0 * 768 + h);
  const float4 v1 = *(const float4*)(b2 + e1 * 768 + h);
  float4 r;
  r.x = w0 * v0.x + w1 * v1.x; r.y = w0 * v0.y + w1 * v1.y;
  r.z = w0 * v0.z + w1 * v1.z; r.w = w0 * v0.w + w1 * v1.w;
  *(float4*)(out + (size_t)b * 512 * 768 + (size_t)idx * 4) = r;
}

// ---------- GEMM2 split-K x8: out[b] += hbuf_k @ W2[e_k] (fp32 atomics) ----------
// grid (6 ntiles, 4 mtiles, 64 = 8 b x 8 ksplits); each split = 12 BK64 steps
__global__ void gemm2_kernel(const u16* __restrict__ hbuf, const u16* __restrict__ w2t,
                             float* __restrict__ out,
                             const int* __restrict__ sel) {
  __shared__ __align__(16) u16 As[128 * 64];
  __shared__ __align__(16) u16 Bs[128 * 64];
  const int z = blockIdx.z;
  const int b = z >> 3, ks = z & 7;
  const int kslot = ks >> 2;                        // which of the 2 experts
  const int e = sel[b * 2 + kslot];
  const u16* A = hbuf + (size_t)(b * 2 + kslot) * 512 * 3072;
  const u16* Bt = w2t + (size_t)e * 768 * 3072;
  const int kbase = (ks & 3) * 768;                 // quarter of the expert's K=3072
  const int m0 = blockIdx.y * 128, n0 = blockIdx.x * 128;
  const int tid = threadIdx.x, lane = tid & 63;
  const int wv = tid >> 6;
  const int wm = (wv >> 1) * 64, wn = (wv & 1) * 64;
  const int mi = lane & 15, kq = lane >> 4;

  f32x4 acc[4][4] = {};
  for (int t = 0; t < 12; ++t) {
    const int k0 = kbase + t * 64;
    __syncthreads();
    stage_tile(A, 3072, m0, k0, As, tid);
    stage_tile(Bt, 3072, n0, k0, Bs, tid);
    __syncthreads();
    mfma_step(As, Bs, wm, wn, mi, kq, acc);
  }

  float* C = out + (size_t)b * 512 * 768;
#pragma unroll
  for (int nt = 0; nt < 4; ++nt) {
    const int col = n0 + wn + nt * 16 + mi;
#pragma unroll
    for (int mt = 0; mt < 4; ++mt) {
#pragma unroll
      for (int r = 0; r < 4; ++r) {
        const int row = m0 + wm + mt * 16 + kq * 4 + r;
        atomicAdd(&C[(size_t)row * 768 + col], acc[mt][nt][r]);
      }
    }
  }
}

extern "C" void kernel_launch(void* const* d_in, const int* in_sizes, int n_in,
                              void* d_out, int out_size, void* d_ws, size_t ws_size,
                              hipStream_t stream) {
  const float* hidden = (const float*)d_in[0];  // [8,512,768] fp32
  const float* Wg     = (const float*)d_in[1];  // [768,8]
  const float* W1     = (const float*)d_in[2];  // [8,768,3072]
  const float* b1     = (const float*)d_in[3];  // [8,3072]
  const float* W2     = (const float*)d_in[4];  // [8,3072,768]
  const float* b2     = (const float*)d_in[5];  // [8,768]
  float* out = (float*)d_out;                   // [8,512,768] ++ logits [8,8], fp32

  char* ws = (char*)d_ws;
  int*   sel    = (int*)ws;                     // [16]
  float* wsel   = (float*)(ws + 64);            // [16]
  float* pooled = (float*)(ws + 128);           // [8][768] fp32 (zeroed below)
  u16* hbf  = (u16*)(ws + 32768);               // [8][512][768] bf16
  u16* wT   = hbf + (size_t)8 * 512 * 768;      // [8][3072][768] bf16 (w1t, then w2t)
  u16* hbuf = wT + (size_t)8 * 3072 * 768;      // [16][512][3072] bf16

  float* logits_out = out + (size_t)8 * 512 * 768;

  hipMemsetAsync(ws, 0, 32768, stream);  // zero sel/wsel/pooled
  convert_pool_kernel<<<dim3(64, 8), 192, 0, stream>>>(hidden, hbf, pooled);
  router_final_kernel<<<1, 256, 0, stream>>>(pooled, Wg, logits_out, sel, wsel);
  transpose_kernel<<<dim3(48, 12, 8), 128, 0, stream>>>(W1, wT, 768, 3072);   // [H,F]->[F,H]
  gemm1_kernel<<<dim3(24, 4, 16), 256, 0, stream>>>(hbf, wT, b1, hbuf, sel, wsel);
  transpose_kernel<<<dim3(12, 48, 8), 128, 0, stream>>>(W2, wT, 3072, 768);   // [F,H]->[H,F]
  init_out_kernel<<<dim3(384, 8), 256, 0, stream>>>(b2, out, sel, wsel);
  gemm2_kernel<<<dim3(6, 4, 64), 256, 0, stream>>>(hbuf, wT, out, sel);
}